// Round 5
// baseline (527.054 us; speedup 1.0000x reference)
//
#include <hip/hip_runtime.h>
#include <hip/hip_bf16.h>
#include <cstdint>
#include <cstddef>

typedef __attribute__((ext_vector_type(8))) short short8;
typedef __attribute__((ext_vector_type(4))) float f32x4;

#define AS1U32(p) ((const __attribute__((address_space(1))) uint32_t*)(p))
#define AS3U32(p) ((__attribute__((address_space(3))) uint32_t*)(p))

__device__ __forceinline__ unsigned short f2bf(float v) {
  union { float f; uint32_t u; } a; a.f = v;
  uint32_t u = a.u;
  u += 0x7FFFu + ((u >> 16) & 1u);   // round-to-nearest-even
  return (unsigned short)(u >> 16);
}

// gelu(x) = x * sigmoid(2u), u = sqrt(2/pi)(x + 0.044715 x^3)
__device__ __forceinline__ float gelu_fast(float x) {
  const float c0 = 0.7978845608028654f;
  const float c1 = 0.044715f;
  float u = c0 * (x + c1 * x * x * x);
  return x * __builtin_amdgcn_rcpf(1.0f + __expf(-2.0f * u));
}

// ---------------- prologue kernels ----------------

// partial token-sums: kpart[b*512+d] = sum_{i<64} x[(b*64+i)*512+d]
__global__ __launch_bounds__(512)
void reduce_part(const float* __restrict__ x, float* __restrict__ kpart) {
  const int d = threadIdx.x;
  const int b = blockIdx.x;
  float s = 0.f;
#pragma unroll 4
  for (int i = 0; i < 64; i++)
    s += x[((size_t)b * 64 + i) * 512 + d];
  kpart[(size_t)b * 512 + d] = s;
}

// one block, 1024 threads: finish ksum, 16 parallel coarse dots, top-4, biases
__global__ __launch_bounds__(1024)
void gate_all(const float* __restrict__ kpart,
              const float* __restrict__ gate_w,
              const float* __restrict__ gate_b,
              const float* __restrict__ b1, const float* __restrict__ b2,
              int* __restrict__ idxout,
              float* __restrict__ b1cat, float* __restrict__ b2sel) {
  __shared__ float ksum2[2][512];
  __shared__ float coarse[16];
  __shared__ int idxl[4];
  const int t = threadIdx.x;
  {
    const int d = t & 511, h = t >> 9;
    float s = 0.f;
    for (int p = h * 128; p < h * 128 + 128; p++) s += kpart[(size_t)p * 512 + d];
    ksum2[h][d] = s;
  }
  __syncthreads();
  {
    const int wave = t >> 6, lane = t & 63;
    const int d0 = lane * 8;
    float s = 0.f;
#pragma unroll
    for (int j = 0; j < 8; j++)
      s += gate_w[wave * 512 + d0 + j] * (ksum2[0][d0 + j] + ksum2[1][d0 + j]);
#pragma unroll
    for (int off = 32; off >= 1; off >>= 1) s += __shfl_down(s, off, 64);
    if (lane == 0) coarse[wave] = s + gate_b[wave];
  }
  __syncthreads();
  if (t == 0) {
    unsigned taken = 0;
    for (int r = 0; r < 4; r++) {
      float best = -3.4e38f; int bi = 0;
      for (int e = 0; e < 16; e++)
        if (!((taken >> e) & 1u) && coarse[e] > best) { best = coarse[e]; bi = e; }
      taken |= 1u << bi;
      idxl[r] = bi; idxout[r] = bi;
    }
  }
  __syncthreads();
  for (int i = t; i < 8192; i += 1024)
    b1cat[i] = b1[(size_t)idxl[i >> 11] * 2048 + (i & 2047)];
  for (int i = t; i < 2048; i += 1024)
    b2sel[i] = b2[(size_t)idxl[i >> 9] * 512 + (i & 511)];
}

// merged: weight transposes (blocks 0..2047) + per-token softmax gate & x->bf16
// (blocks 2048..6143). Saves one graph node (~13us dispatch overhead each).
__global__ __launch_bounds__(256)
void prep_all(const float* __restrict__ w1, const float* __restrict__ w2,
              unsigned short* __restrict__ w1t, unsigned short* __restrict__ w2t,
              const float* __restrict__ x,
              const float* __restrict__ gate_w,
              const float* __restrict__ gate_b,
              const int* __restrict__ idx,
              float* __restrict__ gwout,
              unsigned short* __restrict__ xbf) {
  const int tid = threadIdx.x;
  const int bid = blockIdx.x;
  if (bid < 2048) {
    // ---- transpose + fp32->bf16 ----
    __shared__ float tl[64][65];
    const int ty = tid >> 6, tx = tid & 63;
    const int z = bid >> 8, bx = (bid >> 5) & 7, by = bid & 31;
    const float* src; unsigned short* dbase; int C, dstLd, r0, c0;
    if (z < 4) {
      // W1: [512 x 2048] at idx[z] -> w1t[(z*2048+f)*512 + d]
      src = w1 + (size_t)idx[z] * 512 * 2048;
      dbase = w1t + (size_t)z * 2048 * 512;
      C = 2048; dstLd = 512;
      r0 = bx * 64; c0 = by * 64;
    } else {
      // W2: [2048 x 512] at idx[z-4] -> w2t[d*8192 + (z-4)*2048 + f]
      src = w2 + (size_t)idx[z - 4] * 2048 * 512;
      dbase = w2t + (size_t)(z - 4) * 2048;
      C = 512; dstLd = 8192;
      r0 = by * 64; c0 = bx * 64;
    }
#pragma unroll
    for (int i = 0; i < 16; i++) {
      int r = ty * 16 + i;
      tl[r][tx] = src[(size_t)(r0 + r) * C + c0 + tx];
    }
    __syncthreads();
#pragma unroll
    for (int i = 0; i < 16; i++) {
      int rr = ty * 16 + i;
      dbase[(size_t)(c0 + rr) * dstLd + r0 + tx] = f2bf(tl[tx][rr]);
    }
  } else {
    // ---- softmax gate + x conversion ----
    __shared__ float wsel[4][512];
    __shared__ float bsel[4];
    for (int i = tid; i < 2048; i += 256) {
      int k = i >> 9;
      wsel[k][i & 511] = gate_w[(size_t)idx[k] * 512 + (i & 511)];
    }
    if (tid < 4) bsel[tid] = gate_b[idx[tid]];
    __syncthreads();
    const int wave = tid >> 6, lane = tid & 63;
    const int t = (bid - 2048) * 4 + wave;
    const float* xr = x + (size_t)t * 512 + lane * 8;
    float4 v0 = ((const float4*)xr)[0];
    float4 v1 = ((const float4*)xr)[1];
    float vals[8] = {v0.x, v0.y, v0.z, v0.w, v1.x, v1.y, v1.z, v1.w};
    short8 pk;
#pragma unroll
    for (int j = 0; j < 8; j++) pk[j] = (short)f2bf(vals[j]);
    *(short8*)(xbf + (size_t)t * 512 + lane * 8) = pk;
    float a0 = 0.f, a1 = 0.f, a2 = 0.f, a3 = 0.f;
    const int dbase = lane * 8;
#pragma unroll
    for (int j = 0; j < 8; j++) {
      float xv = vals[j];
      a0 += xv * wsel[0][dbase + j];
      a1 += xv * wsel[1][dbase + j];
      a2 += xv * wsel[2][dbase + j];
      a3 += xv * wsel[3][dbase + j];
    }
#pragma unroll
    for (int off = 32; off >= 1; off >>= 1) {
      a0 += __shfl_down(a0, off, 64);
      a1 += __shfl_down(a1, off, 64);
      a2 += __shfl_down(a2, off, 64);
      a3 += __shfl_down(a3, off, 64);
    }
    if (lane == 0) {
      float l0 = a0 + bsel[0], l1 = a1 + bsel[1], l2 = a2 + bsel[2], l3 = a3 + bsel[3];
      float m = fmaxf(fmaxf(l0, l1), fmaxf(l2, l3));
      float e0 = __expf(l0 - m), e1 = __expf(l1 - m);
      float e2 = __expf(l2 - m), e3 = __expf(l3 - m);
      float inv = 1.0f / (e0 + e1 + e2 + e3);
      float* o = gwout + (size_t)t * 4;
      o[0] = e0 * inv; o[1] = e1 * inv; o[2] = e2 * inv; o[3] = e3 * inv;
    }
  }
}

// ---------------- GEMM1: 128x128 tile ----------------
// C[M x N] = A[M x K(lda)] * Bt[N x K(ldb)]^T (bf16, K-contig rows)
// Cb[r*ldc+n] = bf16( gw[r,kexp] * gelu(acc + bias[colOff+n]) )
__global__ __launch_bounds__(256, 2)
void gemm1(const unsigned short* __restrict__ A,
           const unsigned short* __restrict__ Bt,
           unsigned short* __restrict__ Cb, int K, int lda, int ldb, int ldc,
           const float* __restrict__ gw,
           const float* __restrict__ bias, int colOff) {
  __shared__ unsigned short lA[128 * 64];
  __shared__ unsigned short lB[128 * 64];
  const int tid = threadIdx.x;
  const int wave = tid >> 6;
  const int lane = tid & 63;
  const int rowA0 = blockIdx.x * 128;
  const int rowB0 = blockIdx.y * 128;

  f32x4 acc[4][4];
#pragma unroll
  for (int i = 0; i < 4; i++)
#pragma unroll
    for (int j = 0; j < 4; j++) acc[i][j] = (f32x4){0.f, 0.f, 0.f, 0.f};

  const int lrow = lane >> 3;
  const int lslot = lane & 7;
  const int gchunk = lslot ^ lrow;     // store-side XOR swizzle (16B granule)
  const int fr = lane & 15;
  const int quad = lane >> 4;
  const int wm = (wave >> 1) * 64;
  const int wn = (wave & 1) * 64;
  const int swz = fr & 7;

  for (int kt = 0; kt < K; kt += 64) {
#pragma unroll
    for (int c = 0; c < 4; c++) {
      int r = wave * 32 + c * 8 + lrow;
      const unsigned short* gp = A + (size_t)(rowA0 + r) * lda + kt + gchunk * 8;
      __builtin_amdgcn_global_load_lds(AS1U32(gp), AS3U32(lA + (wave * 32 + c * 8) * 64), 16, 0, 0);
    }
#pragma unroll
    for (int c = 0; c < 4; c++) {
      int r = wave * 32 + c * 8 + lrow;
      const unsigned short* gp = Bt + (size_t)(rowB0 + r) * ldb + kt + gchunk * 8;
      __builtin_amdgcn_global_load_lds(AS1U32(gp), AS3U32(lB + (wave * 32 + c * 8) * 64), 16, 0, 0);
    }
    __syncthreads();
#pragma unroll
    for (int ks = 0; ks < 2; ks++) {
      short8 af[4], bfr[4];
      const int c = ks * 4 + quad;
      const int slot = (c ^ swz) << 3;
#pragma unroll
      for (int i = 0; i < 4; i++)
        af[i] = *(const short8*)(lA + (wm + i * 16 + fr) * 64 + slot);
#pragma unroll
      for (int j = 0; j < 4; j++)
        bfr[j] = *(const short8*)(lB + (wn + j * 16 + fr) * 64 + slot);
#pragma unroll
      for (int i = 0; i < 4; i++)
#pragma unroll
        for (int j = 0; j < 4; j++)
          acc[i][j] = __builtin_amdgcn_mfma_f32_16x16x32_bf16(af[i], bfr[j], acc[i][j], 0, 0, 0);
    }
    __syncthreads();
  }

  const int kexp = (colOff + rowB0) >> 11;
#pragma unroll
  for (int i = 0; i < 4; i++) {
#pragma unroll
    for (int reg = 0; reg < 4; reg++) {
      int r = rowA0 + wm + i * 16 + quad * 4 + reg;
      float g = gw[(size_t)r * 4 + kexp];
#pragma unroll
      for (int j = 0; j < 4; j++) {
        int n = rowB0 + wn + j * 16 + fr;
        float v = acc[i][j][reg] + bias[colOff + n];
        Cb[(size_t)r * ldc + n] = f2bf(gelu_fast(v) * g);
      }
    }
  }
}

// ---------------- GEMM2: 64x128 tile (grid 256x4 = 4 blocks/CU) ----------------
// Cf[r*512+n] = acc + (accum ? Cf[..] : sum_k gw[r,k]*bias[k*512+n])
__global__ __launch_bounds__(256)
void gemm2(const unsigned short* __restrict__ A,
           const unsigned short* __restrict__ Bt,
           float* __restrict__ Cf, int K, int lda, int ldb,
           const float* __restrict__ gw,
           const float* __restrict__ bias, int accum) {
  __shared__ unsigned short lA[64 * 64];    //  8 KB
  __shared__ unsigned short lB[128 * 64];   // 16 KB
  const int tid = threadIdx.x;
  const int wave = tid >> 6;
  const int lane = tid & 63;
  const int rowA0 = blockIdx.x * 64;
  const int rowB0 = blockIdx.y * 128;

  f32x4 acc[2][4];
#pragma unroll
  for (int i = 0; i < 2; i++)
#pragma unroll
    for (int j = 0; j < 4; j++) acc[i][j] = (f32x4){0.f, 0.f, 0.f, 0.f};

  const int lrow = lane >> 3;
  const int lslot = lane & 7;
  const int gchunk = lslot ^ lrow;
  const int fr = lane & 15;
  const int quad = lane >> 4;
  const int wm = (wave >> 1) * 32;   // waves 2x2: wave tile 32 x 64
  const int wn = (wave & 1) * 64;
  const int swz = fr & 7;

  for (int kt = 0; kt < K; kt += 64) {
#pragma unroll
    for (int c = 0; c < 2; c++) {    // A: 64 rows
      int r = wave * 16 + c * 8 + lrow;
      const unsigned short* gp = A + (size_t)(rowA0 + r) * lda + kt + gchunk * 8;
      __builtin_amdgcn_global_load_lds(AS1U32(gp), AS3U32(lA + (wave * 16 + c * 8) * 64), 16, 0, 0);
    }
#pragma unroll
    for (int c = 0; c < 4; c++) {    // B: 128 rows
      int r = wave * 32 + c * 8 + lrow;
      const unsigned short* gp = Bt + (size_t)(rowB0 + r) * ldb + kt + gchunk * 8;
      __builtin_amdgcn_global_load_lds(AS1U32(gp), AS3U32(lB + (wave * 32 + c * 8) * 64), 16, 0, 0);
    }
    __syncthreads();
#pragma unroll
    for (int ks = 0; ks < 2; ks++) {
      short8 af[2], bfr[4];
      const int c = ks * 4 + quad;
      const int slot = (c ^ swz) << 3;
#pragma unroll
      for (int i = 0; i < 2; i++)
        af[i] = *(const short8*)(lA + (wm + i * 16 + fr) * 64 + slot);
#pragma unroll
      for (int j = 0; j < 4; j++)
        bfr[j] = *(const short8*)(lB + (wn + j * 16 + fr) * 64 + slot);
#pragma unroll
      for (int i = 0; i < 2; i++)
#pragma unroll
        for (int j = 0; j < 4; j++)
          acc[i][j] = __builtin_amdgcn_mfma_f32_16x16x32_bf16(af[i], bfr[j], acc[i][j], 0, 0, 0);
    }
    __syncthreads();
  }

#pragma unroll
  for (int i = 0; i < 2; i++) {
#pragma unroll
    for (int reg = 0; reg < 4; reg++) {
      int r = rowA0 + wm + i * 16 + quad * 4 + reg;
      size_t t4 = (size_t)r * 4;
      float g0 = gw[t4], g1 = gw[t4 + 1], g2 = gw[t4 + 2], g3 = gw[t4 + 3];
#pragma unroll
      for (int j = 0; j < 4; j++) {
        int n = rowB0 + wn + j * 16 + fr;
        size_t ci = (size_t)r * 512 + n;
        float v = acc[i][j][reg];
        if (accum) v += Cf[ci];
        else v += g0 * bias[n] + g1 * bias[512 + n] +
                  g2 * bias[1024 + n] + g3 * bias[1536 + n];
        Cf[ci] = v;
      }
    }
  }
}

// ---------------- launch ----------------

extern "C" void kernel_launch(void* const* d_in, const int* in_sizes, int n_in,
                              void* d_out, int out_size, void* d_ws, size_t ws_size,
                              hipStream_t stream) {
  (void)in_sizes; (void)n_in; (void)out_size;
  const float* x      = (const float*)d_in[0];
  const float* gate_w = (const float*)d_in[1];
  const float* gate_b = (const float*)d_in[2];
  const float* w1     = (const float*)d_in[3];
  const float* b1     = (const float*)d_in[4];
  const float* w2     = (const float*)d_in[5];
  const float* b2     = (const float*)d_in[6];

  char* ws = (char*)d_ws;
  int*            idx   = (int*)(ws + 0);                //  16 B
  float*          gw    = (float*)(ws + 4096);           // 256 KB  [T,4]
  float*          b1cat = (float*)(ws + 266240);         //  32 KB
  float*          b2sel = (float*)(ws + 299008);         //   8 KB
  float*          kpart = (float*)(ws + 307200);         // 512 KB  [256,512]
  unsigned short* xbf   = (unsigned short*)(ws + 831488);      // 16.8 MB [T,512]
  unsigned short* w1t   = (unsigned short*)(ws + 17608704);    //  8.4 MB [8192,512]
  unsigned short* w2t   = (unsigned short*)(ws + 25997312);    //  8.4 MB [512,8192]
  unsigned short* hbuf  = (unsigned short*)(ws + 34385920);    // h' slab
  const size_t HBUF_OFF = 34385920;

  // DF-slab: h' slab = [16384 x slabDF] bf16; fewest slabs that fit.
  size_t avail = ws_size > HBUF_OFF ? ws_size - HBUF_OFF : 0;
  int nslab = 1;
  while (nslab < 16 && (size_t)16384 * (8192 / nslab) * 2 > avail) nslab <<= 1;
  const int slabDF = 8192 / nslab;

  reduce_part<<<256, 512, 0, stream>>>(x, kpart);
  gate_all<<<1, 1024, 0, stream>>>(kpart, gate_w, gate_b, b1, b2, idx, b1cat, b2sel);
  prep_all<<<6144, 256, 0, stream>>>(w1, w2, w1t, w2t, x, gate_w, gate_b, idx, gw, xbf);

  for (int s = 0; s < nslab; s++) {
    const int c0 = s * slabDF;
    gemm1<<<dim3(128, slabDF / 128), 256, 0, stream>>>(
        xbf, w1t + (size_t)c0 * 512, hbuf,
        /*K=*/512, /*lda=*/512, /*ldb=*/512, /*ldc=*/slabDF,
        gw, b1cat, c0);
    gemm2<<<dim3(256, 4), 256, 0, stream>>>(
        hbuf, w2t + c0, (float*)d_out,
        /*K=*/slabDF, /*lda=*/slabDF, /*ldb=*/8192,
        gw, b2sel, s > 0);
  }
}

// Round 6
// 526.537 us; speedup vs baseline: 1.0010x; 1.0010x over previous
//
#include <hip/hip_runtime.h>
#include <hip/hip_bf16.h>
#include <cstdint>
#include <cstddef>

typedef __attribute__((ext_vector_type(8))) short short8;
typedef __attribute__((ext_vector_type(4))) float f32x4;

#define AS1U32(p) ((const __attribute__((address_space(1))) uint32_t*)(p))
#define AS3U32(p) ((__attribute__((address_space(3))) uint32_t*)(p))

__device__ __forceinline__ unsigned short f2bf(float v) {
  union { float f; uint32_t u; } a; a.f = v;
  uint32_t u = a.u;
  u += 0x7FFFu + ((u >> 16) & 1u);   // round-to-nearest-even
  return (unsigned short)(u >> 16);
}

// gelu(x) = x * sigmoid(2u), u = sqrt(2/pi)(x + 0.044715 x^3)
__device__ __forceinline__ float gelu_fast(float x) {
  const float c0 = 0.7978845608028654f;
  const float c1 = 0.044715f;
  float u = c0 * (x + c1 * x * x * x);
  return x * __builtin_amdgcn_rcpf(1.0f + __expf(-2.0f * u));
}

// ---------------- prologue kernels ----------------

// partial token-sums, f32x4-vectorized: kpart[b*512+d] = sum_{i<64} x[(b*64+i)*512+d]
__global__ __launch_bounds__(512)
void reduce_part(const float* __restrict__ x, float* __restrict__ kpart) {
  const int q = threadIdx.x & 127;   // d-quad
  const int sub = threadIdx.x >> 7;  // token subgroup 0..3
  f32x4 s = (f32x4){0.f, 0.f, 0.f, 0.f};
#pragma unroll 4
  for (int i = 0; i < 16; i++) {
    int t = blockIdx.x * 64 + sub * 16 + i;
    s += *(const f32x4*)&x[(size_t)t * 512 + q * 4];
  }
  __shared__ f32x4 red[4][128];
  red[sub][q] = s;
  __syncthreads();
  if (threadIdx.x < 128) {
    f32x4 r = red[0][q] + red[1][q] + red[2][q] + red[3][q];
    *(f32x4*)&kpart[(size_t)blockIdx.x * 512 + q * 4] = r;
  }
}

// one block, 1024 threads: finish ksum, 16 parallel coarse dots, top-4, biases
__global__ __launch_bounds__(1024)
void gate_all(const float* __restrict__ kpart,
              const float* __restrict__ gate_w,
              const float* __restrict__ gate_b,
              const float* __restrict__ b1, const float* __restrict__ b2,
              int* __restrict__ idxout,
              float* __restrict__ b1cat, float* __restrict__ b2sel) {
  __shared__ float ksum2[2][512];
  __shared__ float coarse[16];
  __shared__ int idxl[4];
  const int t = threadIdx.x;
  {
    const int d = t & 511, h = t >> 9;
    float s = 0.f;
    for (int p = h * 128; p < h * 128 + 128; p++) s += kpart[(size_t)p * 512 + d];
    ksum2[h][d] = s;
  }
  __syncthreads();
  {
    const int wave = t >> 6, lane = t & 63;
    const int d0 = lane * 8;
    float s = 0.f;
#pragma unroll
    for (int j = 0; j < 8; j++)
      s += gate_w[wave * 512 + d0 + j] * (ksum2[0][d0 + j] + ksum2[1][d0 + j]);
#pragma unroll
    for (int off = 32; off >= 1; off >>= 1) s += __shfl_down(s, off, 64);
    if (lane == 0) coarse[wave] = s + gate_b[wave];
  }
  __syncthreads();
  if (t == 0) {
    unsigned taken = 0;
    for (int r = 0; r < 4; r++) {
      float best = -3.4e38f; int bi = 0;
      for (int e = 0; e < 16; e++)
        if (!((taken >> e) & 1u) && coarse[e] > best) { best = coarse[e]; bi = e; }
      taken |= 1u << bi;
      idxl[r] = bi; idxout[r] = bi;
    }
  }
  __syncthreads();
  for (int i = t; i < 8192; i += 1024)
    b1cat[i] = b1[(size_t)idxl[i >> 11] * 2048 + (i & 2047)];
  for (int i = t; i < 2048; i += 1024)
    b2sel[i] = b2[(size_t)idxl[i >> 9] * 512 + (i & 511)];
}

// merged: weight transposes (blocks 0..2047, float4 loads) + per-token softmax
// gate & x->bf16 (blocks 2048..6143).
__global__ __launch_bounds__(256)
void prep_all(const float* __restrict__ w1, const float* __restrict__ w2,
              unsigned short* __restrict__ w1t, unsigned short* __restrict__ w2t,
              const float* __restrict__ x,
              const float* __restrict__ gate_w,
              const float* __restrict__ gate_b,
              const int* __restrict__ idx,
              float* __restrict__ gwout,
              unsigned short* __restrict__ xbf) {
  const int tid = threadIdx.x;
  const int bid = blockIdx.x;
  if (bid < 2048) {
    // ---- transpose + fp32->bf16 ----
    __shared__ float tl[64][65];
    const int z = bid >> 8, bx = (bid >> 5) & 7, by = bid & 31;
    const float* src; unsigned short* dbase; int C, dstLd, r0, c0;
    if (z < 4) {
      // W1: [512 x 2048] at idx[z] -> w1t[(z*2048+f)*512 + d]
      src = w1 + (size_t)idx[z] * 512 * 2048;
      dbase = w1t + (size_t)z * 2048 * 512;
      C = 2048; dstLd = 512;
      r0 = bx * 64; c0 = by * 64;
    } else {
      // W2: [2048 x 512] at idx[z-4] -> w2t[d*8192 + (z-4)*2048 + f]
      src = w2 + (size_t)idx[z - 4] * 2048 * 512;
      dbase = w2t + (size_t)(z - 4) * 2048;
      C = 512; dstLd = 8192;
      r0 = by * 64; c0 = bx * 64;
    }
    // load phase: float4 per thread, 4 rows each
    const int c4 = (tid & 15) * 4;
    const int rw = tid >> 4;          // 0..15
#pragma unroll
    for (int i = 0; i < 4; i++) {
      int r = rw + i * 16;
      float4 v = *(const float4*)&src[(size_t)(r0 + r) * C + c0 + c4];
      tl[r][c4] = v.x; tl[r][c4 + 1] = v.y; tl[r][c4 + 2] = v.z; tl[r][c4 + 3] = v.w;
    }
    __syncthreads();
    const int ty = tid >> 6, tx = tid & 63;
#pragma unroll
    for (int i = 0; i < 16; i++) {
      int rr = ty * 16 + i;
      dbase[(size_t)(c0 + rr) * dstLd + r0 + tx] = f2bf(tl[tx][rr]);
    }
  } else {
    // ---- softmax gate + x conversion ----
    __shared__ float wsel[4][512];
    __shared__ float bsel[4];
    for (int i = tid; i < 2048; i += 256) {
      int k = i >> 9;
      wsel[k][i & 511] = gate_w[(size_t)idx[k] * 512 + (i & 511)];
    }
    if (tid < 4) bsel[tid] = gate_b[idx[tid]];
    __syncthreads();
    const int wave = tid >> 6, lane = tid & 63;
    const int t = (bid - 2048) * 4 + wave;
    const float* xr = x + (size_t)t * 512 + lane * 8;
    float4 v0 = ((const float4*)xr)[0];
    float4 v1 = ((const float4*)xr)[1];
    float vals[8] = {v0.x, v0.y, v0.z, v0.w, v1.x, v1.y, v1.z, v1.w};
    short8 pk;
#pragma unroll
    for (int j = 0; j < 8; j++) pk[j] = (short)f2bf(vals[j]);
    *(short8*)(xbf + (size_t)t * 512 + lane * 8) = pk;
    float a0 = 0.f, a1 = 0.f, a2 = 0.f, a3 = 0.f;
    const int dbase = lane * 8;
#pragma unroll
    for (int j = 0; j < 8; j++) {
      float xv = vals[j];
      a0 += xv * wsel[0][dbase + j];
      a1 += xv * wsel[1][dbase + j];
      a2 += xv * wsel[2][dbase + j];
      a3 += xv * wsel[3][dbase + j];
    }
#pragma unroll
    for (int off = 32; off >= 1; off >>= 1) {
      a0 += __shfl_down(a0, off, 64);
      a1 += __shfl_down(a1, off, 64);
      a2 += __shfl_down(a2, off, 64);
      a3 += __shfl_down(a3, off, 64);
    }
    if (lane == 0) {
      float l0 = a0 + bsel[0], l1 = a1 + bsel[1], l2 = a2 + bsel[2], l3 = a3 + bsel[3];
      float m = fmaxf(fmaxf(l0, l1), fmaxf(l2, l3));
      float e0 = __expf(l0 - m), e1 = __expf(l1 - m);
      float e2 = __expf(l2 - m), e3 = __expf(l3 - m);
      float inv = 1.0f / (e0 + e1 + e2 + e3);
      float* o = gwout + (size_t)t * 4;
      o[0] = e0 * inv; o[1] = e1 * inv; o[2] = e2 * inv; o[3] = e3 * inv;
    }
  }
}

// ---------------- GEMM1: 128x128 tile ----------------
// Cb[r*ldc+n] = bf16( gw[r,kexp] * gelu(acc + bias[colOff+n]) )
__global__ __launch_bounds__(256, 2)
void gemm1(const unsigned short* __restrict__ A,
           const unsigned short* __restrict__ Bt,
           unsigned short* __restrict__ Cb, int K, int lda, int ldb, int ldc,
           const float* __restrict__ gw,
           const float* __restrict__ bias, int colOff) {
  __shared__ unsigned short lA[128 * 64];
  __shared__ unsigned short lB[128 * 64];
  const int tid = threadIdx.x;
  const int wave = tid >> 6;
  const int lane = tid & 63;
  const int rowA0 = blockIdx.x * 128;
  const int rowB0 = blockIdx.y * 128;

  f32x4 acc[4][4];
#pragma unroll
  for (int i = 0; i < 4; i++)
#pragma unroll
    for (int j = 0; j < 4; j++) acc[i][j] = (f32x4){0.f, 0.f, 0.f, 0.f};

  const int lrow = lane >> 3;
  const int lslot = lane & 7;
  const int gchunk = lslot ^ lrow;     // store-side XOR swizzle (16B granule)
  const int fr = lane & 15;
  const int quad = lane >> 4;
  const int wm = (wave >> 1) * 64;
  const int wn = (wave & 1) * 64;
  const int swz = fr & 7;

  for (int kt = 0; kt < K; kt += 64) {
#pragma unroll
    for (int c = 0; c < 4; c++) {
      int r = wave * 32 + c * 8 + lrow;
      const unsigned short* gp = A + (size_t)(rowA0 + r) * lda + kt + gchunk * 8;
      __builtin_amdgcn_global_load_lds(AS1U32(gp), AS3U32(lA + (wave * 32 + c * 8) * 64), 16, 0, 0);
    }
#pragma unroll
    for (int c = 0; c < 4; c++) {
      int r = wave * 32 + c * 8 + lrow;
      const unsigned short* gp = Bt + (size_t)(rowB0 + r) * ldb + kt + gchunk * 8;
      __builtin_amdgcn_global_load_lds(AS1U32(gp), AS3U32(lB + (wave * 32 + c * 8) * 64), 16, 0, 0);
    }
    __syncthreads();
#pragma unroll
    for (int ks = 0; ks < 2; ks++) {
      short8 af[4], bfr[4];
      const int c = ks * 4 + quad;
      const int slot = (c ^ swz) << 3;
#pragma unroll
      for (int i = 0; i < 4; i++)
        af[i] = *(const short8*)(lA + (wm + i * 16 + fr) * 64 + slot);
#pragma unroll
      for (int j = 0; j < 4; j++)
        bfr[j] = *(const short8*)(lB + (wn + j * 16 + fr) * 64 + slot);
#pragma unroll
      for (int i = 0; i < 4; i++)
#pragma unroll
        for (int j = 0; j < 4; j++)
          acc[i][j] = __builtin_amdgcn_mfma_f32_16x16x32_bf16(af[i], bfr[j], acc[i][j], 0, 0, 0);
    }
    __syncthreads();
  }

  const int kexp = (colOff + rowB0) >> 11;
#pragma unroll
  for (int i = 0; i < 4; i++) {
#pragma unroll
    for (int reg = 0; reg < 4; reg++) {
      int r = rowA0 + wm + i * 16 + quad * 4 + reg;
      float g = gw[(size_t)r * 4 + kexp];
#pragma unroll
      for (int j = 0; j < 4; j++) {
        int n = rowB0 + wn + j * 16 + fr;
        float v = acc[i][j][reg] + bias[colOff + n];
        Cb[(size_t)r * ldc + n] = f2bf(gelu_fast(v) * g);
      }
    }
  }
}

// ---------------- GEMM2: 128x128 tile (reverted from 64x128 — R5 showed
// traffic/intensity beats occupancy here) ----------------
// Cf[r*512+n] = acc + (accum ? Cf[..] : sum_k gw[r,k]*bias[k*512+n])
__global__ __launch_bounds__(256, 2)
void gemm2(const unsigned short* __restrict__ A,
           const unsigned short* __restrict__ Bt,
           float* __restrict__ Cf, int K, int lda, int ldb,
           const float* __restrict__ gw,
           const float* __restrict__ bias, int accum) {
  __shared__ unsigned short lA[128 * 64];
  __shared__ unsigned short lB[128 * 64];
  const int tid = threadIdx.x;
  const int wave = tid >> 6;
  const int lane = tid & 63;
  const int rowA0 = blockIdx.x * 128;
  const int rowB0 = blockIdx.y * 128;

  f32x4 acc[4][4];
#pragma unroll
  for (int i = 0; i < 4; i++)
#pragma unroll
    for (int j = 0; j < 4; j++) acc[i][j] = (f32x4){0.f, 0.f, 0.f, 0.f};

  const int lrow = lane >> 3;
  const int lslot = lane & 7;
  const int gchunk = lslot ^ lrow;
  const int fr = lane & 15;
  const int quad = lane >> 4;
  const int wm = (wave >> 1) * 64;
  const int wn = (wave & 1) * 64;
  const int swz = fr & 7;

  for (int kt = 0; kt < K; kt += 64) {
#pragma unroll
    for (int c = 0; c < 4; c++) {
      int r = wave * 32 + c * 8 + lrow;
      const unsigned short* gp = A + (size_t)(rowA0 + r) * lda + kt + gchunk * 8;
      __builtin_amdgcn_global_load_lds(AS1U32(gp), AS3U32(lA + (wave * 32 + c * 8) * 64), 16, 0, 0);
    }
#pragma unroll
    for (int c = 0; c < 4; c++) {
      int r = wave * 32 + c * 8 + lrow;
      const unsigned short* gp = Bt + (size_t)(rowB0 + r) * ldb + kt + gchunk * 8;
      __builtin_amdgcn_global_load_lds(AS1U32(gp), AS3U32(lB + (wave * 32 + c * 8) * 64), 16, 0, 0);
    }
    __syncthreads();
#pragma unroll
    for (int ks = 0; ks < 2; ks++) {
      short8 af[4], bfr[4];
      const int c = ks * 4 + quad;
      const int slot = (c ^ swz) << 3;
#pragma unroll
      for (int i = 0; i < 4; i++)
        af[i] = *(const short8*)(lA + (wm + i * 16 + fr) * 64 + slot);
#pragma unroll
      for (int j = 0; j < 4; j++)
        bfr[j] = *(const short8*)(lB + (wn + j * 16 + fr) * 64 + slot);
#pragma unroll
      for (int i = 0; i < 4; i++)
#pragma unroll
        for (int j = 0; j < 4; j++)
          acc[i][j] = __builtin_amdgcn_mfma_f32_16x16x32_bf16(af[i], bfr[j], acc[i][j], 0, 0, 0);
    }
    __syncthreads();
  }

#pragma unroll
  for (int i = 0; i < 4; i++) {
#pragma unroll
    for (int reg = 0; reg < 4; reg++) {
      int r = rowA0 + wm + i * 16 + quad * 4 + reg;
      size_t t4 = (size_t)r * 4;
      float g0 = gw[t4], g1 = gw[t4 + 1], g2 = gw[t4 + 2], g3 = gw[t4 + 3];
#pragma unroll
      for (int j = 0; j < 4; j++) {
        int n = rowB0 + wn + j * 16 + fr;
        size_t ci = (size_t)r * 512 + n;
        float v = acc[i][j][reg];
        if (accum) v += Cf[ci];
        else v += g0 * bias[n] + g1 * bias[512 + n] +
                  g2 * bias[1024 + n] + g3 * bias[1536 + n];
        Cf[ci] = v;
      }
    }
  }
}

// ---------------- launch ----------------

extern "C" void kernel_launch(void* const* d_in, const int* in_sizes, int n_in,
                              void* d_out, int out_size, void* d_ws, size_t ws_size,
                              hipStream_t stream) {
  (void)in_sizes; (void)n_in; (void)out_size;
  const float* x      = (const float*)d_in[0];
  const float* gate_w = (const float*)d_in[1];
  const float* gate_b = (const float*)d_in[2];
  const float* w1     = (const float*)d_in[3];
  const float* b1     = (const float*)d_in[4];
  const float* w2     = (const float*)d_in[5];
  const float* b2     = (const float*)d_in[6];

  char* ws = (char*)d_ws;
  int*            idx   = (int*)(ws + 0);                //  16 B
  float*          gw    = (float*)(ws + 4096);           // 256 KB  [T,4]
  float*          b1cat = (float*)(ws + 266240);         //  32 KB
  float*          b2sel = (float*)(ws + 299008);         //   8 KB
  float*          kpart = (float*)(ws + 307200);         // 512 KB  [256,512]
  unsigned short* xbf   = (unsigned short*)(ws + 831488);      // 16.8 MB [T,512]
  unsigned short* w1t   = (unsigned short*)(ws + 17608704);    //  8.4 MB [8192,512]
  unsigned short* w2t   = (unsigned short*)(ws + 25997312);    //  8.4 MB [512,8192]
  unsigned short* hbuf  = (unsigned short*)(ws + 34385920);    // h' slab
  const size_t HBUF_OFF = 34385920;

  // DF-slab: h' slab = [16384 x slabDF] bf16; fewest slabs that fit.
  size_t avail = ws_size > HBUF_OFF ? ws_size - HBUF_OFF : 0;
  int nslab = 1;
  while (nslab < 16 && (size_t)16384 * (8192 / nslab) * 2 > avail) nslab <<= 1;
  const int slabDF = 8192 / nslab;

  reduce_part<<<256, 512, 0, stream>>>(x, kpart);
  gate_all<<<1, 1024, 0, stream>>>(kpart, gate_w, gate_b, b1, b2, idx, b1cat, b2sel);
  prep_all<<<6144, 256, 0, stream>>>(w1, w2, w1t, w2t, x, gate_w, gate_b, idx, gw, xbf);

  for (int s = 0; s < nslab; s++) {
    const int c0 = s * slabDF;
    gemm1<<<dim3(128, slabDF / 128), 256, 0, stream>>>(
        xbf, w1t + (size_t)c0 * 512, hbuf,
        /*K=*/512, /*lda=*/512, /*ldb=*/512, /*ldc=*/slabDF,
        gw, b1cat, c0);
    gemm2<<<dim3(128, 4), 256, 0, stream>>>(
        hbuf, w2t + c0, (float*)d_out,
        /*K=*/slabDF, /*lda=*/slabDF, /*ldb=*/8192,
        gw, b2sel, s > 0);
  }
}